// Round 3
// baseline (498.401 us; speedup 1.0000x reference)
//
#include <hip/hip_runtime.h>

// KWinnersTakeAll: x (B=4096, D=16384) fp32. k_active = 820.
// threshold = (topv[819] + topv[820]) * 0.5 (descending top-k), mask = x > thr.
// v4: phase-diversity config. BLOCK=512, VPT=8 (32 data VGPRs), 4 blocks/CU
// (launch_bounds(512,8) caps VGPR at 64) so ~4 independent blocks per CU sit
// at different phases (load/hist/select/store) and HBM stays busy.
// 2-way privatized histogram (waves alternate copies) halves DS contention.
// One block per row; 1024-bin histogram selection; exact candidate ranking;
// bitwise radix-select fallback (over registers) for pathological rows.

#define DDIM   16384
#define BLOCK  512
#define VPT    8            // float4 per thread = 32 floats
#define NBINS  1024
#define CAP    1024
#define R1     819u
#define R2     820u

__device__ __forceinline__ unsigned f2k(float f) {
    unsigned u = __float_as_uint(f);
    return u ^ ((unsigned)((int)u >> 31) | 0x80000000u);
}
__device__ __forceinline__ float k2f(unsigned k) {
    unsigned u = (k & 0x80000000u) ? (k ^ 0x80000000u) : ~k;
    return __uint_as_float(u);
}
__device__ __forceinline__ int val2bin(float x) {
    // bin = floor((x + 8) * 64), clamped to [0, 1023]. Monotone in x.
    float t = floorf(fmaf(x, 64.0f, 512.0f));
    t = fminf(fmaxf(t, 0.0f), 1023.0f);
    return (int)t;
}

__global__ __launch_bounds__(BLOCK, 8)
void kwta_kernel(const float* __restrict__ x, float* __restrict__ out) {
    __shared__ unsigned hist[2][NBINS];              // 8 KB (2-way privatized)
    __shared__ float cand[CAP];                      // 4 KB
    __shared__ unsigned s_candCount;
    __shared__ int s_b1, s_b2;
    __shared__ unsigned s_above;
    __shared__ float s_v1, s_v2;
    __shared__ unsigned s_redc[BLOCK / 64];
    __shared__ unsigned s_redm[BLOCK / 64];
    __shared__ unsigned s_total;

    const int tid = threadIdx.x;
    const size_t base = (size_t)blockIdx.x * DDIM;
    const float4* __restrict__ x4 = (const float4*)(x + base);
    float4* __restrict__ o4 = (float4*)(out + base);

    hist[0][tid] = 0u; hist[0][tid + BLOCK] = 0u;
    hist[1][tid] = 0u; hist[1][tid + BLOCK] = 0u;
    if (tid == 0) s_candCount = 0u;
    __syncthreads();

    // ---- Pass A: load row into registers + histogram ----
    // (unrolled: compiler hoists the 8 independent loads, then drains them
    //  one-by-one into the atomics — load latency overlaps hist work)
    float4 d[VPT];
    unsigned* myhist = hist[(tid >> 6) & 1];
#pragma unroll
    for (int j = 0; j < VPT; ++j) {
        d[j] = x4[j * BLOCK + tid];
        atomicAdd(&myhist[val2bin(d[j].x)], 1u);
        atomicAdd(&myhist[val2bin(d[j].y)], 1u);
        atomicAdd(&myhist[val2bin(d[j].z)], 1u);
        atomicAdd(&myhist[val2bin(d[j].w)], 1u);
    }
    __syncthreads();

    // ---- Locate bins holding descending ranks R1, R2 (wave 0 only) ----
    if (tid < 64) {
        int c = tid;
        int top = (NBINS - 1) - (c << 4);   // chunk covers bins [top-15, top]
        unsigned s = 0;
#pragma unroll
        for (int i = 0; i < 16; ++i) s += hist[0][top - i] + hist[1][top - i];
        unsigned v = s;
#pragma unroll
        for (int dd = 1; dd < 64; dd <<= 1) {
            unsigned u = __shfl_up(v, dd, 64);
            if (c >= dd) v += u;
        }
        unsigned cum = v - s;               // elements in all chunks above this one
#pragma unroll
        for (int i = 0; i < 16; ++i) {
            unsigned h = hist[0][top - i] + hist[1][top - i];
            if (R1 >= cum && R1 < cum + h) { s_b1 = top - i; s_above = cum; }
            if (R2 >= cum && R2 < cum + h) { s_b2 = top - i; }
            cum += h;
        }
    }
    __syncthreads();

    const int b1 = s_b1, b2 = s_b2;
    const unsigned above = s_above;

    // ---- Pass B: compact candidates from bins [b2, b1] (from registers) ----
#pragma unroll
    for (int j = 0; j < VPT; ++j) {
        float vals[4] = {d[j].x, d[j].y, d[j].z, d[j].w};
#pragma unroll
        for (int q = 0; q < 4; ++q) {
            int b = val2bin(vals[q]);
            if (b >= b2 && b <= b1) {
                unsigned p = atomicAdd(&s_candCount, 1u);
                if (p < CAP) cand[p] = vals[q];
            }
        }
    }
    __syncthreads();

    const unsigned C = s_candCount;
    if (C <= CAP) {
        // ---- Exact ranking among candidates ----
        for (unsigned j = tid; j < C; j += BLOCK) {
            float xj = cand[j];
            unsigned g = 0, e = 0;
            for (unsigned i = 0; i < C; ++i) {
                float xi = cand[i];
                g += (xi > xj) ? 1u : 0u;
                e += (xi == xj) ? 1u : 0u;
            }
            unsigned lo = above + g, hi = lo + e;
            if (R1 >= lo && R1 < hi) s_v1 = xj;
            if (R2 >= lo && R2 < hi) s_v2 = xj;
        }
    } else {
        // ---- Fallback: exact bitwise radix select over sortable keys (regs) ----
        unsigned prefix = 0, r = R1;
        for (int bit = 31; bit >= 0; --bit) {
            unsigned hiMask = (bit == 31) ? 0u : ~((1u << (bit + 1)) - 1u);
            unsigned bitMask = 1u << bit;
            unsigned cnt = 0;
#pragma unroll
            for (int j = 0; j < VPT; ++j) {
                unsigned k0 = f2k(d[j].x), k1 = f2k(d[j].y);
                unsigned k2 = f2k(d[j].z), k3 = f2k(d[j].w);
                cnt += (((k0 & hiMask) == prefix) && (k0 & bitMask)) ? 1u : 0u;
                cnt += (((k1 & hiMask) == prefix) && (k1 & bitMask)) ? 1u : 0u;
                cnt += (((k2 & hiMask) == prefix) && (k2 & bitMask)) ? 1u : 0u;
                cnt += (((k3 & hiMask) == prefix) && (k3 & bitMask)) ? 1u : 0u;
            }
#pragma unroll
            for (int dd = 32; dd >= 1; dd >>= 1) cnt += __shfl_xor(cnt, dd, 64);
            if ((tid & 63) == 0) s_redc[tid >> 6] = cnt;
            __syncthreads();
            if (tid == 0) {
                unsigned t = 0;
                for (int w = 0; w < BLOCK / 64; ++w) t += s_redc[w];
                s_total = t;
            }
            __syncthreads();
            unsigned c1 = s_total;
            if (r < c1) prefix |= bitMask; else r -= c1;
            __syncthreads();
        }
        unsigned K1 = prefix;
        unsigned cge = 0, mb = 0;
#pragma unroll
        for (int j = 0; j < VPT; ++j) {
            unsigned ks[4] = {f2k(d[j].x), f2k(d[j].y), f2k(d[j].z), f2k(d[j].w)};
#pragma unroll
            for (int q = 0; q < 4; ++q) {
                unsigned k = ks[q];
                if (k >= K1) cge++; else mb = mb > k ? mb : k;
            }
        }
#pragma unroll
        for (int dd = 32; dd >= 1; dd >>= 1) {
            cge += __shfl_xor(cge, dd, 64);
            unsigned om = __shfl_xor(mb, dd, 64);
            mb = mb > om ? mb : om;
        }
        if ((tid & 63) == 0) { s_redc[tid >> 6] = cge; s_redm[tid >> 6] = mb; }
        __syncthreads();
        if (tid == 0) {
            unsigned t = 0, m = 0;
            for (int w = 0; w < BLOCK / 64; ++w) {
                t += s_redc[w];
                m = m > s_redm[w] ? m : s_redm[w];
            }
            unsigned K2 = (t >= R2 + 1u) ? K1 : m;
            s_v1 = k2f(K1);
            s_v2 = k2f(K2);
        }
    }
    __syncthreads();

    const float thr = (s_v1 + s_v2) * 0.5f;

    // ---- Pass C: mask from registers -> global ----
#pragma unroll
    for (int j = 0; j < VPT; ++j) {
        float4 f = d[j];
        float4 m;
        m.x = (f.x > thr) ? 1.0f : 0.0f;
        m.y = (f.y > thr) ? 1.0f : 0.0f;
        m.z = (f.z > thr) ? 1.0f : 0.0f;
        m.w = (f.w > thr) ? 1.0f : 0.0f;
        o4[j * BLOCK + tid] = m;
    }
}

extern "C" void kernel_launch(void* const* d_in, const int* in_sizes, int n_in,
                              void* d_out, int out_size, void* d_ws, size_t ws_size,
                              hipStream_t stream) {
    const float* x = (const float*)d_in[0];
    float* out = (float*)d_out;
    int batch = in_sizes[0] / DDIM;
    kwta_kernel<<<batch, BLOCK, 0, stream>>>(x, out);
}

// Round 5
// 456.587 us; speedup vs baseline: 1.0916x; 1.0916x over previous
//
#include <hip/hip_runtime.h>

// KWinnersTakeAll: x (B=4096, D=16384) fp32. k_active = 820.
// threshold = (topv[819] + topv[820]) * 0.5 (descending top-k), mask = x > thr.
// v5: no-spill phase-diversity geometry. BLOCK=256, VPT=16 (64 data VGPRs),
// __launch_bounds__(256,4) -> VGPR cap 128 (fits: 64 data + ~40 temps, NO
// spill -- v4's (512,8)/64-cap spilled d[] to scratch: VGPR_Count=32,
// WRITE_SIZE showed +256MiB of spill stores). 4 blocks/CU x 4 waves = 16
// waves/CU: four independent phase domains per CU so HBM stays busy while
// other blocks are in hist/select phases (v4 counters: hbm 51% = 2-block
// phase-lock duty cycle). Algorithm unchanged: 1024-bin histogram selection,
// exact candidate ranking, bitwise radix-select fallback over registers.
// (Resubmission of round-3 kernel: round-4 bench was an infra failure,
// "MI355X container failed twice" at acquire; no compile/run signal.)

#define DDIM   16384
#define BLOCK  256
#define VPT    16           // float4 per thread = 64 floats
#define NBINS  1024
#define CAP    1024
#define R1     819u
#define R2     820u

__device__ __forceinline__ unsigned f2k(float f) {
    unsigned u = __float_as_uint(f);
    return u ^ ((unsigned)((int)u >> 31) | 0x80000000u);
}
__device__ __forceinline__ float k2f(unsigned k) {
    unsigned u = (k & 0x80000000u) ? (k ^ 0x80000000u) : ~k;
    return __uint_as_float(u);
}
__device__ __forceinline__ int val2bin(float x) {
    // bin = floor((x + 8) * 64), clamped to [0, 1023]. Monotone in x.
    float t = floorf(fmaf(x, 64.0f, 512.0f));
    t = fminf(fmaxf(t, 0.0f), 1023.0f);
    return (int)t;
}

__global__ __launch_bounds__(BLOCK, 4)
void kwta_kernel(const float* __restrict__ x, float* __restrict__ out) {
    __shared__ unsigned hist[NBINS];                 // 4 KB
    __shared__ float cand[CAP];                      // 4 KB
    __shared__ unsigned s_candCount;
    __shared__ int s_b1, s_b2;
    __shared__ unsigned s_above;
    __shared__ float s_v1, s_v2;
    __shared__ unsigned s_redc[BLOCK / 64];
    __shared__ unsigned s_redm[BLOCK / 64];
    __shared__ unsigned s_total;

    const int tid = threadIdx.x;
    const size_t base = (size_t)blockIdx.x * DDIM;
    const float4* __restrict__ x4 = (const float4*)(x + base);
    float4* __restrict__ o4 = (float4*)(out + base);

    hist[tid] = 0u;
    hist[tid + 256] = 0u;
    hist[tid + 512] = 0u;
    hist[tid + 768] = 0u;
    if (tid == 0) s_candCount = 0u;

    // ---- Load row into registers (coalesced, 16B/lane, 16 in flight) ----
    float4 d[VPT];
#pragma unroll
    for (int j = 0; j < VPT; ++j) d[j] = x4[j * BLOCK + tid];

    __syncthreads();   // hist cleared

    // ---- Pass A: histogram from registers ----
    // (loads above are all in flight; compiler drains them chunk-by-chunk
    //  with per-use waitcnt, so early atomics overlap late loads)
#pragma unroll
    for (int j = 0; j < VPT; ++j) {
        atomicAdd(&hist[val2bin(d[j].x)], 1u);
        atomicAdd(&hist[val2bin(d[j].y)], 1u);
        atomicAdd(&hist[val2bin(d[j].z)], 1u);
        atomicAdd(&hist[val2bin(d[j].w)], 1u);
    }
    __syncthreads();

    // ---- Locate bins holding descending ranks R1, R2 (wave 0 only) ----
    if (tid < 64) {
        int c = tid;
        int top = (NBINS - 1) - (c << 4);   // chunk covers bins [top-15, top]
        unsigned s = 0;
#pragma unroll
        for (int i = 0; i < 16; ++i) s += hist[top - i];
        unsigned v = s;
#pragma unroll
        for (int dd = 1; dd < 64; dd <<= 1) {
            unsigned u = __shfl_up(v, dd, 64);
            if (c >= dd) v += u;
        }
        unsigned cum = v - s;               // elements in all chunks above this one
#pragma unroll
        for (int i = 0; i < 16; ++i) {
            unsigned h = hist[top - i];
            if (R1 >= cum && R1 < cum + h) { s_b1 = top - i; s_above = cum; }
            if (R2 >= cum && R2 < cum + h) { s_b2 = top - i; }
            cum += h;
        }
    }
    __syncthreads();

    const int b1 = s_b1, b2 = s_b2;
    const unsigned above = s_above;

    // ---- Pass B: compact candidates from bins [b2, b1] (from registers) ----
#pragma unroll
    for (int j = 0; j < VPT; ++j) {
        float vals[4] = {d[j].x, d[j].y, d[j].z, d[j].w};
#pragma unroll
        for (int q = 0; q < 4; ++q) {
            int b = val2bin(vals[q]);
            if (b >= b2 && b <= b1) {
                unsigned p = atomicAdd(&s_candCount, 1u);
                if (p < CAP) cand[p] = vals[q];
            }
        }
    }
    __syncthreads();

    const unsigned C = s_candCount;
    if (C <= CAP) {
        // ---- Exact ranking among candidates ----
        for (unsigned j = tid; j < C; j += BLOCK) {
            float xj = cand[j];
            unsigned g = 0, e = 0;
            for (unsigned i = 0; i < C; ++i) {
                float xi = cand[i];
                g += (xi > xj) ? 1u : 0u;
                e += (xi == xj) ? 1u : 0u;
            }
            unsigned lo = above + g, hi = lo + e;
            if (R1 >= lo && R1 < hi) s_v1 = xj;
            if (R2 >= lo && R2 < hi) s_v2 = xj;
        }
    } else {
        // ---- Fallback: exact bitwise radix select over sortable keys (regs) ----
        unsigned prefix = 0, r = R1;
        for (int bit = 31; bit >= 0; --bit) {
            unsigned hiMask = (bit == 31) ? 0u : ~((1u << (bit + 1)) - 1u);
            unsigned bitMask = 1u << bit;
            unsigned cnt = 0;
#pragma unroll
            for (int j = 0; j < VPT; ++j) {
                unsigned k0 = f2k(d[j].x), k1 = f2k(d[j].y);
                unsigned k2 = f2k(d[j].z), k3 = f2k(d[j].w);
                cnt += (((k0 & hiMask) == prefix) && (k0 & bitMask)) ? 1u : 0u;
                cnt += (((k1 & hiMask) == prefix) && (k1 & bitMask)) ? 1u : 0u;
                cnt += (((k2 & hiMask) == prefix) && (k2 & bitMask)) ? 1u : 0u;
                cnt += (((k3 & hiMask) == prefix) && (k3 & bitMask)) ? 1u : 0u;
            }
#pragma unroll
            for (int dd = 32; dd >= 1; dd >>= 1) cnt += __shfl_xor(cnt, dd, 64);
            if ((tid & 63) == 0) s_redc[tid >> 6] = cnt;
            __syncthreads();
            if (tid == 0) {
                unsigned t = 0;
                for (int w = 0; w < BLOCK / 64; ++w) t += s_redc[w];
                s_total = t;
            }
            __syncthreads();
            unsigned c1 = s_total;
            if (r < c1) prefix |= bitMask; else r -= c1;
            __syncthreads();
        }
        unsigned K1 = prefix;
        unsigned cge = 0, mb = 0;
#pragma unroll
        for (int j = 0; j < VPT; ++j) {
            unsigned ks[4] = {f2k(d[j].x), f2k(d[j].y), f2k(d[j].z), f2k(d[j].w)};
#pragma unroll
            for (int q = 0; q < 4; ++q) {
                unsigned k = ks[q];
                if (k >= K1) cge++; else mb = mb > k ? mb : k;
            }
        }
#pragma unroll
        for (int dd = 32; dd >= 1; dd >>= 1) {
            cge += __shfl_xor(cge, dd, 64);
            unsigned om = __shfl_xor(mb, dd, 64);
            mb = mb > om ? mb : om;
        }
        if ((tid & 63) == 0) { s_redc[tid >> 6] = cge; s_redm[tid >> 6] = mb; }
        __syncthreads();
        if (tid == 0) {
            unsigned t = 0, m = 0;
            for (int w = 0; w < BLOCK / 64; ++w) {
                t += s_redc[w];
                m = m > s_redm[w] ? m : s_redm[w];
            }
            unsigned K2 = (t >= R2 + 1u) ? K1 : m;
            s_v1 = k2f(K1);
            s_v2 = k2f(K2);
        }
    }
    __syncthreads();

    const float thr = (s_v1 + s_v2) * 0.5f;

    // ---- Pass C: mask from registers -> global ----
#pragma unroll
    for (int j = 0; j < VPT; ++j) {
        float4 f = d[j];
        float4 m;
        m.x = (f.x > thr) ? 1.0f : 0.0f;
        m.y = (f.y > thr) ? 1.0f : 0.0f;
        m.z = (f.z > thr) ? 1.0f : 0.0f;
        m.w = (f.w > thr) ? 1.0f : 0.0f;
        o4[j * BLOCK + tid] = m;
    }
}

extern "C" void kernel_launch(void* const* d_in, const int* in_sizes, int n_in,
                              void* d_out, int out_size, void* d_ws, size_t ws_size,
                              hipStream_t stream) {
    const float* x = (const float*)d_in[0];
    float* out = (float*)d_out;
    int batch = in_sizes[0] / DDIM;
    kwta_kernel<<<batch, BLOCK, 0, stream>>>(x, out);
}

// Round 6
// 446.879 us; speedup vs baseline: 1.1153x; 1.0217x over previous
//
#include <hip/hip_runtime.h>

// KWinnersTakeAll: x (B=4096, D=16384) fp32. k_active = 820.
// threshold = (topv[819] + topv[820]) * 0.5 (descending top-k), mask = x > thr.
//
// v6: intra-block software pipeline. Evidence: v3 (2 blk/CU, 32 waves) kernel
// ~137us, v5 (4 blk/CU, 16 waves) ~159us -> block-level phase diversity does
// NOT fill HBM idle time; __syncthreads' vmcnt(0) drain at every barrier kills
// any load overlap (compiler emits s_waitcnt vmcnt(0) lgkmcnt(0) before
// s_barrier). Fix: each block processes ROWS=8 consecutive rows with
// register double-buffering; next row's global loads are issued BEFORE the
// current row's hist/scan/compact/rank phases, which are separated by raw
// __builtin_amdgcn_s_barrier() + s_waitcnt lgkmcnt(0) ONLY (no vmcnt drain,
// cf. learn_hip 8-phase counted-vmcnt discipline). Prefetch stays in flight
// under the ~2.5us select phase -> HBM duty ~60% -> ~90%.
// BLOCK=512, VPT=8 per row, 2 buffers = 64 data VGPRs; launch_bounds(512,4)
// -> 128 VGPR cap (~95 used, no spill; v4 proved 64-cap spills), 2 blocks/CU.
// Algorithm unchanged: 1024-bin histogram selection, exact candidate ranking,
// bitwise radix-select fallback (uniform branch, __syncthreads inside is OK).

#define DDIM   16384
#define BLOCK  512
#define VPT    8            // float4 per thread per row = 32 floats
#define ROWS   8            // rows per block
#define NBINS  1024
#define CAP    1024
#define R1     819u
#define R2     820u

// Raw workgroup barrier WITHOUT vmcnt drain: commit LDS ops (lgkmcnt(0)),
// then s_barrier. Global prefetch loads stay in flight across it.
#define LBAR() do {                                          \
    asm volatile("s_waitcnt lgkmcnt(0)" ::: "memory");       \
    __builtin_amdgcn_s_barrier();                            \
} while (0)

__device__ __forceinline__ unsigned f2k(float f) {
    unsigned u = __float_as_uint(f);
    return u ^ ((unsigned)((int)u >> 31) | 0x80000000u);
}
__device__ __forceinline__ float k2f(unsigned k) {
    unsigned u = (k & 0x80000000u) ? (k ^ 0x80000000u) : ~k;
    return __uint_as_float(u);
}
__device__ __forceinline__ int val2bin(float x) {
    // bin = floor((x + 8) * 64), clamped to [0, 1023]. Monotone in x.
    float t = floorf(fmaf(x, 64.0f, 512.0f));
    t = fminf(fmaxf(t, 0.0f), 1023.0f);
    return (int)t;
}

__device__ __forceinline__ void process_row(
    float4 (&cur)[VPT],                 // current row (registers)
    float4 (&pre)[VPT],                 // prefetch destination buffer
    const float4* __restrict__ xnext,   // next row source
    bool do_pre,
    float4* __restrict__ odst,          // output row (float4)
    int tid,
    unsigned* hist, float* cand,
    unsigned* s_candCount, int* s_b1, int* s_b2, unsigned* s_above,
    float* s_v1, float* s_v2,
    unsigned* s_redc, unsigned* s_redm, unsigned* s_total)
{
    // ---- 1. issue prefetch of next row (no wait; pinned above LBAR by asm) ----
    if (do_pre) {
#pragma unroll
        for (int j = 0; j < VPT; ++j) pre[j] = xnext[j * BLOCK + tid];
    }

    // ---- 2. zero hist + candCount ----
    hist[tid] = 0u;
    hist[tid + BLOCK] = 0u;
    if (tid == 0) *s_candCount = 0u;
    LBAR();                               // hist zeroed, visible

    // ---- 3. histogram from registers (compiler waits counted vmcnt on cur) ----
#pragma unroll
    for (int j = 0; j < VPT; ++j) {
        atomicAdd(&hist[val2bin(cur[j].x)], 1u);
        atomicAdd(&hist[val2bin(cur[j].y)], 1u);
        atomicAdd(&hist[val2bin(cur[j].z)], 1u);
        atomicAdd(&hist[val2bin(cur[j].w)], 1u);
    }
    LBAR();                               // histogram complete

    // ---- 4. locate bins holding descending ranks R1, R2 (wave 0 only) ----
    if (tid < 64) {
        int c = tid;
        int top = (NBINS - 1) - (c << 4);   // chunk covers bins [top-15, top]
        unsigned s = 0;
#pragma unroll
        for (int i = 0; i < 16; ++i) s += hist[top - i];
        unsigned v = s;
#pragma unroll
        for (int dd = 1; dd < 64; dd <<= 1) {
            unsigned u = __shfl_up(v, dd, 64);
            if (c >= dd) v += u;
        }
        unsigned cum = v - s;               // elements in all chunks above
#pragma unroll
        for (int i = 0; i < 16; ++i) {
            unsigned h = hist[top - i];
            if (R1 >= cum && R1 < cum + h) { *s_b1 = top - i; *s_above = cum; }
            if (R2 >= cum && R2 < cum + h) { *s_b2 = top - i; }
            cum += h;
        }
    }
    LBAR();                               // b1/b2/above visible

    const int b1 = *s_b1, b2 = *s_b2;
    const unsigned above = *s_above;

    // ---- 5. compact candidates from bins [b2, b1] ----
#pragma unroll
    for (int j = 0; j < VPT; ++j) {
        float vals[4] = {cur[j].x, cur[j].y, cur[j].z, cur[j].w};
#pragma unroll
        for (int q = 0; q < 4; ++q) {
            int b = val2bin(vals[q]);
            if (b >= b2 && b <= b1) {
                unsigned p = atomicAdd(s_candCount, 1u);
                if (p < CAP) cand[p] = vals[q];
            }
        }
    }
    LBAR();                               // cand + count visible

    const unsigned C = *s_candCount;
    if (C <= CAP) {
        // ---- 6. exact ranking among candidates ----
        for (unsigned j = tid; j < C; j += BLOCK) {
            float xj = cand[j];
            unsigned g = 0, e = 0;
            for (unsigned i = 0; i < C; ++i) {
                float xi = cand[i];
                g += (xi > xj) ? 1u : 0u;
                e += (xi == xj) ? 1u : 0u;
            }
            unsigned lo = above + g, hi = lo + e;
            if (R1 >= lo && R1 < hi) *s_v1 = xj;
            if (R2 >= lo && R2 < hi) *s_v2 = xj;
        }
    } else {
        // ---- fallback: exact bitwise radix select over registers ----
        // (uniform branch; __syncthreads' vmcnt drain is harmless here —
        //  this path is never taken for non-pathological rows)
        unsigned prefix = 0, r = R1;
        for (int bit = 31; bit >= 0; --bit) {
            unsigned hiMask = (bit == 31) ? 0u : ~((1u << (bit + 1)) - 1u);
            unsigned bitMask = 1u << bit;
            unsigned cnt = 0;
#pragma unroll
            for (int j = 0; j < VPT; ++j) {
                unsigned k0 = f2k(cur[j].x), k1 = f2k(cur[j].y);
                unsigned k2 = f2k(cur[j].z), k3 = f2k(cur[j].w);
                cnt += (((k0 & hiMask) == prefix) && (k0 & bitMask)) ? 1u : 0u;
                cnt += (((k1 & hiMask) == prefix) && (k1 & bitMask)) ? 1u : 0u;
                cnt += (((k2 & hiMask) == prefix) && (k2 & bitMask)) ? 1u : 0u;
                cnt += (((k3 & hiMask) == prefix) && (k3 & bitMask)) ? 1u : 0u;
            }
#pragma unroll
            for (int dd = 32; dd >= 1; dd >>= 1) cnt += __shfl_xor(cnt, dd, 64);
            if ((tid & 63) == 0) s_redc[tid >> 6] = cnt;
            __syncthreads();
            if (tid == 0) {
                unsigned t = 0;
                for (int w = 0; w < BLOCK / 64; ++w) t += s_redc[w];
                *s_total = t;
            }
            __syncthreads();
            unsigned c1 = *s_total;
            if (r < c1) prefix |= bitMask; else r -= c1;
            __syncthreads();
        }
        unsigned K1 = prefix;
        unsigned cge = 0, mb = 0;
#pragma unroll
        for (int j = 0; j < VPT; ++j) {
            unsigned ks[4] = {f2k(cur[j].x), f2k(cur[j].y), f2k(cur[j].z), f2k(cur[j].w)};
#pragma unroll
            for (int q = 0; q < 4; ++q) {
                unsigned k = ks[q];
                if (k >= K1) cge++; else mb = mb > k ? mb : k;
            }
        }
#pragma unroll
        for (int dd = 32; dd >= 1; dd >>= 1) {
            cge += __shfl_xor(cge, dd, 64);
            unsigned om = __shfl_xor(mb, dd, 64);
            mb = mb > om ? mb : om;
        }
        if ((tid & 63) == 0) { s_redc[tid >> 6] = cge; s_redm[tid >> 6] = mb; }
        __syncthreads();
        if (tid == 0) {
            unsigned t = 0, m = 0;
            for (int w = 0; w < BLOCK / 64; ++w) {
                t += s_redc[w];
                m = m > s_redm[w] ? m : s_redm[w];
            }
            unsigned K2 = (t >= R2 + 1u) ? K1 : m;
            *s_v1 = k2f(K1);
            *s_v2 = k2f(K2);
        }
    }
    LBAR();                               // v1/v2 visible

    const float thr = (*s_v1 + *s_v2) * 0.5f;

    // ---- 7. store mask (no wait; drains under next row's select phase) ----
#pragma unroll
    for (int j = 0; j < VPT; ++j) {
        float4 f = cur[j];
        float4 m;
        m.x = (f.x > thr) ? 1.0f : 0.0f;
        m.y = (f.y > thr) ? 1.0f : 0.0f;
        m.z = (f.z > thr) ? 1.0f : 0.0f;
        m.w = (f.w > thr) ? 1.0f : 0.0f;
        odst[j * BLOCK + tid] = m;
    }
}

__global__ __launch_bounds__(BLOCK, 4)
void kwta_kernel(const float* __restrict__ x, float* __restrict__ out) {
    __shared__ unsigned hist[NBINS];                 // 4 KB
    __shared__ float cand[CAP];                      // 4 KB
    __shared__ unsigned s_candCount;
    __shared__ int s_b1, s_b2;
    __shared__ unsigned s_above;
    __shared__ float s_v1, s_v2;
    __shared__ unsigned s_redc[BLOCK / 64];
    __shared__ unsigned s_redm[BLOCK / 64];
    __shared__ unsigned s_total;

    const int tid = threadIdx.x;
    const size_t rowbase = (size_t)blockIdx.x * ROWS;
    const float4* __restrict__ x4 = (const float4*)(x + rowbase * DDIM);
    float4* __restrict__ o4 = (float4*)(out + rowbase * DDIM);
    const int S4 = DDIM / 4;                         // float4 per row

    float4 A[VPT], B[VPT];

    // prologue: load row 0 -> A
#pragma unroll
    for (int j = 0; j < VPT; ++j) A[j] = x4[j * BLOCK + tid];

    for (int rp = 0; rp < ROWS / 2; ++rp) {
        const int r0 = 2 * rp;
        // process row r0 from A, prefetch row r0+1 -> B
        process_row(A, B, x4 + (size_t)(r0 + 1) * S4, true,
                    o4 + (size_t)r0 * S4, tid,
                    hist, cand, &s_candCount, &s_b1, &s_b2, &s_above,
                    &s_v1, &s_v2, s_redc, s_redm, &s_total);
        // process row r0+1 from B, prefetch row r0+2 -> A (except last pair)
        process_row(B, A, x4 + (size_t)(r0 + 2) * S4, rp < ROWS / 2 - 1,
                    o4 + (size_t)(r0 + 1) * S4, tid,
                    hist, cand, &s_candCount, &s_b1, &s_b2, &s_above,
                    &s_v1, &s_v2, s_redc, s_redm, &s_total);
    }
}

extern "C" void kernel_launch(void* const* d_in, const int* in_sizes, int n_in,
                              void* d_out, int out_size, void* d_ws, size_t ws_size,
                              hipStream_t stream) {
    const float* x = (const float*)d_in[0];
    float* out = (float*)d_out;
    int batch = in_sizes[0] / DDIM;                  // 4096
    int grid = batch / ROWS;                         // 512 blocks
    kwta_kernel<<<grid, BLOCK, 0, stream>>>(x, out);
}